// Round 4
// baseline (2326.335 us; speedup 1.0000x reference)
//
#include <hip/hip_runtime.h>
#include <hip/hip_fp16.h>

// 2-layer LSTM (T=1024, B=1024, H=100) + FC. R4: in-register gate update.
// 64 blocks x 512 threads; block owns 16 batch rows; 1025 epochs, ONE barrier
// per epoch. Gate tiles reordered as t = 4*ublock + q so each lane ends up
// holding i,f,g,o for (4 rows x 1 unit) in registers -> LSTM update fused
// into the GEMM wave, no gates LDS round-trip. h-state double-buffered in
// swizzled LDS (f16); cell state in VGPRs; x staged via 1-epoch-lag register
// pipeline. Waves 0-3: layer-0 (7 ublocks, K=128); waves 4-7: layer-1
// (7 ublocks, K=224: h0|x(zero rows)|bias|h1), lagged one step.

#define T_SEQ 1024

typedef __attribute__((ext_vector_type(8))) _Float16 half8;
typedef __attribute__((ext_vector_type(4))) float f32x4;

__device__ __forceinline__ unsigned short f2h(float f) {
  _Float16 h = (_Float16)f;
  return *reinterpret_cast<unsigned short*>(&h);
}
__device__ __forceinline__ float fast_sig(float x) {
  return __builtin_amdgcn_rcpf(1.0f + __builtin_amdgcn_exp2f(-1.4426950408889634f * x));
}
__device__ __forceinline__ float fast_tanh(float x) {
  return 1.0f - 2.0f * __builtin_amdgcn_rcpf(1.0f + __builtin_amdgcn_exp2f(2.8853900817779268f * x));
}

// B-matrix element (gate row g, k) per layer.
// L0 K-layout: [0,100)=Whh0, 100-102=Wih0, 103=bias0, else 0.
// L1 K-layout: [0,100)=Wih1(h0 input), 103=bias1, [104,204)=Whh1, else 0.
__device__ __forceinline__ float wval0(int g, int k, const float* Wih, const float* Whh,
                                       const float* bih, const float* bhh) {
  if (k < 100) return Whh[g * 100 + k];
  if (k < 103) return Wih[g * 3 + (k - 100)];
  if (k == 103) return bih[g] + bhh[g];
  return 0.f;
}
__device__ __forceinline__ float wval1(int g, int k, const float* Wih, const float* Whh,
                                       const float* bih, const float* bhh) {
  if (k < 100) return Wih[g * 100 + k];
  if (k == 103) return bih[g] + bhh[g];
  if (k >= 104 && k < 204) return Whh[g * 100 + (k - 104)];
  return 0.f;
}

// Per-wave role: LAYER, NJ ublock-jobs (UB0[,UB1]), optional x staging.
// hcat slots: [0,100)=h0, 100-102=x, 103=1.0(bias), [104,204)=h1, rest 0.
// Row stride 512B, swizzle: byte = row*512 + ((2*slot) ^ ((row&7)<<4)).
template<int LAYER, int NJ, int UB0, int UB1, bool XST>
__device__ void role_loop(unsigned short* hbuf, float* h1f,
                          const float* Wih, const float* Whh,
                          const float* bih, const float* bhh,
                          const float* x, int b0, int lane) {
  constexpr int NKS = (LAYER == 0) ? 4 : 7;
  const int r   = lane & 15;          // A row (batch) == B col (unit within ublock)
  const int hi  = lane >> 4;
  const int swz = (r & 7) << 4;

  // ---- resident weight fragments (init only) ----
  half8 wf[NJ * 4 * NKS];
  #pragma unroll
  for (int j = 0; j < NJ; ++j) {
    const int ub = (j == 0) ? UB0 : UB1;
    const int u  = ub * 16 + r;
    #pragma unroll
    for (int q = 0; q < 4; ++q) {
      const int g = q * 100 + u;
      #pragma unroll
      for (int ks = 0; ks < NKS; ++ks) {
        half8 v;
        #pragma unroll
        for (int jj = 0; jj < 8; ++jj) {
          const int k = ks * 32 + hi * 8 + jj;
          float val = 0.f;
          if (u < 100)
            val = (LAYER == 0) ? wval0(g, k, Wih, Whh, bih, bhh)
                               : wval1(g, k, Wih, Whh, bih, bhh);
          v[jj] = (_Float16)val;
        }
        wf[(j * 4 + q) * NKS + ks] = v;
      }
    }
  }

  // ---- x register pipeline (XST wave, lanes<48: 16 rows x 3 ch) ----
  const int bx = lane / 3;
  const int ix = lane - 3 * bx;
  const float* xp = x + (size_t)(b0 + (bx & 15)) * 3072 + ix * 1024;
  float xv0 = 0.f, xv1 = 0.f;
  if (XST && lane < 48) { xv0 = xp[1]; xv1 = xp[2]; }

  float cst[NJ][4];
  #pragma unroll
  for (int j = 0; j < NJ; ++j)
    #pragma unroll
    for (int k = 0; k < 4; ++k) cst[j][k] = 0.f;

  for (int e = 0; e <= T_SEQ; ++e) {
    const int p = e & 1;
    const char* rb = reinterpret_cast<const char*>(hbuf) + p * 8192;
    char*       wb = reinterpret_cast<char*>(hbuf) + (p ^ 1) * 8192;
    const bool active = (LAYER == 0) ? (e < T_SEQ) : (e >= 1);
    if (active) {
      half8 a[NKS];
      #pragma unroll
      for (int ks = 0; ks < NKS; ++ks)
        a[ks] = *reinterpret_cast<const half8*>(rb + r * 512 + ((ks * 64 + hi * 16) ^ swz));
      #pragma unroll
      for (int j = 0; j < NJ; ++j) {
        f32x4 acc0{0,0,0,0}, acc1{0,0,0,0}, acc2{0,0,0,0}, acc3{0,0,0,0};
        #pragma unroll
        for (int ks = 0; ks < NKS; ++ks) {
          acc0 = __builtin_amdgcn_mfma_f32_16x16x32_f16(a[ks], wf[(j*4+0)*NKS+ks], acc0, 0,0,0);
          acc1 = __builtin_amdgcn_mfma_f32_16x16x32_f16(a[ks], wf[(j*4+1)*NKS+ks], acc1, 0,0,0);
          acc2 = __builtin_amdgcn_mfma_f32_16x16x32_f16(a[ks], wf[(j*4+2)*NKS+ks], acc2, 0,0,0);
          acc3 = __builtin_amdgcn_mfma_f32_16x16x32_f16(a[ks], wf[(j*4+3)*NKS+ks], acc3, 0,0,0);
        }
        const int ub = (j == 0) ? UB0 : UB1;
        const int u  = ub * 16 + r;
        if (u < 100) {
          #pragma unroll
          for (int k = 0; k < 4; ++k) {
            float i_ = fast_sig (acc0[k]);
            float f_ = fast_sig (acc1[k]);
            float g_ = fast_tanh(acc2[k]);
            float o_ = fast_sig (acc3[k]);
            cst[j][k] = f_ * cst[j][k] + i_ * g_;
            float h = o_ * fast_tanh(cst[j][k]);
            const int row  = hi * 4 + k;
            const int slot = (LAYER == 0) ? u : (104 + u);
            *reinterpret_cast<unsigned short*>(
                wb + row * 512 + ((slot * 2) ^ ((row & 7) << 4))) = f2h(h);
            if (LAYER == 1 && e == T_SEQ) h1f[row * 100 + u] = h;
          }
        }
      }
    }
    if (XST) {
      if (lane < 48 && e + 1 <= T_SEQ - 1) {
        // write x[e+1] (loaded >=1 epoch ago -> latency hidden) into write-buf
        *reinterpret_cast<unsigned short*>(
            wb + bx * 512 + (((100 + ix) * 2) ^ ((bx & 7) << 4))) = f2h(xv0);
        xv0 = xv1;
        if (e + 3 <= T_SEQ - 1) xv1 = xp[e + 3];
      }
    }
    __syncthreads();
  }
}

__global__ __launch_bounds__(512, 1)
void lstm2_kernel(const float* __restrict__ x,
                  const float* __restrict__ Wih0, const float* __restrict__ Whh0,
                  const float* __restrict__ bih0, const float* __restrict__ bhh0,
                  const float* __restrict__ Wih1, const float* __restrict__ Whh1,
                  const float* __restrict__ bih1, const float* __restrict__ bhh1,
                  const float* __restrict__ fcw, const float* __restrict__ fcb,
                  float* __restrict__ out) {
  __shared__ __align__(16) unsigned short hbuf[2 * 16 * 256];  // 16 KB, dbuf
  __shared__ float h1f[16 * 100];                              // 6.4 KB

  const int tid  = threadIdx.x;
  const int lane = tid & 63;
  const int wid  = tid >> 6;
  const int b0   = blockIdx.x << 4;   // 16 batch rows per block

  for (int i = tid; i < 2 * 16 * 256; i += 512) hbuf[i] = 0;
  __syncthreads();
  if (tid < 32) {       // bias slot 103 = f16 1.0, both buffers
    int tb = tid >> 4, row = tid & 15;
    *reinterpret_cast<unsigned short*>(
        reinterpret_cast<char*>(hbuf) + tb * 8192 + row * 512 +
        ((103 * 2) ^ ((row & 7) << 4))) = 0x3C00u;
  }
  if (tid >= 64 && tid < 112) {   // x[t=0] into buf0
    int s = tid - 64;
    int b = s / 3, i = s - 3 * b;
    *reinterpret_cast<unsigned short*>(
        reinterpret_cast<char*>(hbuf) + b * 512 +
        (((100 + i) * 2) ^ ((b & 7) << 4))) =
        f2h(x[(size_t)(b0 + b) * 3072 + i * 1024]);
  }
  __syncthreads();

  if      (wid == 0) role_loop<0,2,0,1,false>(hbuf,h1f,Wih0,Whh0,bih0,bhh0,x,b0,lane);
  else if (wid == 1) role_loop<0,2,2,3,false>(hbuf,h1f,Wih0,Whh0,bih0,bhh0,x,b0,lane);
  else if (wid == 2) role_loop<0,2,4,5,false>(hbuf,h1f,Wih0,Whh0,bih0,bhh0,x,b0,lane);
  else if (wid == 3) role_loop<0,1,6,6,true >(hbuf,h1f,Wih0,Whh0,bih0,bhh0,x,b0,lane);
  else if (wid == 4) role_loop<1,2,0,1,false>(hbuf,h1f,Wih1,Whh1,bih1,bhh1,x,b0,lane);
  else if (wid == 5) role_loop<1,2,2,3,false>(hbuf,h1f,Wih1,Whh1,bih1,bhh1,x,b0,lane);
  else if (wid == 6) role_loop<1,2,4,5,false>(hbuf,h1f,Wih1,Whh1,bih1,bhh1,x,b0,lane);
  else               role_loop<1,1,6,6,false>(hbuf,h1f,Wih1,Whh1,bih1,bhh1,x,b0,lane);

  // ---- FC: out[b][j] = fc_b[j] + sum_u fc_w[j][u] * h1[T-1][b][u] ----
  if (tid < 160) {
    int b = tid / 10, j = tid - 10 * (tid / 10);
    float acc = fcb[j];
    for (int u = 0; u < 100; ++u)
      acc += fcw[j * 100 + u] * h1f[b * 100 + u];
    out[(size_t)(b0 + b) * 10 + j] = acc;
  }
}

extern "C" void kernel_launch(void* const* d_in, const int* in_sizes, int n_in,
                              void* d_out, int out_size, void* d_ws, size_t ws_size,
                              hipStream_t stream) {
  (void)in_sizes; (void)n_in; (void)d_ws; (void)ws_size; (void)out_size;
  const float* x    = (const float*)d_in[0];
  const float* Wih0 = (const float*)d_in[1];
  const float* Whh0 = (const float*)d_in[2];
  const float* bih0 = (const float*)d_in[3];
  const float* bhh0 = (const float*)d_in[4];
  const float* Wih1 = (const float*)d_in[5];
  const float* Whh1 = (const float*)d_in[6];
  const float* bih1 = (const float*)d_in[7];
  const float* bhh1 = (const float*)d_in[8];
  const float* fcw  = (const float*)d_in[9];
  const float* fcb  = (const float*)d_in[10];
  hipLaunchKernelGGL(lstm2_kernel, dim3(64), dim3(512), 0, stream,
                     x, Wih0, Whh0, bih0, bhh0, Wih1, Whh1, bih1, bhh1,
                     fcw, fcb, (float*)d_out);
}

// Round 6
// 1110.672 us; speedup vs baseline: 2.0945x; 2.0945x over previous
//
#include <hip/hip_runtime.h>
#include <hip/hip_fp16.h>

// 2-layer LSTM (T=1024, B=1024, H=100) + FC. R6: batch-row replication.
// 256 blocks x 4 batch rows, 512 threads, dual-job waves (L0 ublock + L1
// ublock register-resident, asm-pinned against remat/spill). A-fragment reads
// row (r&3) -> A rows are the 4 batch rows replicated 4x -> every lane holds
// batches 0-3 of unit r in its 4 accumulator elements -> select by hi (3
// cndmasks), update (batch hi, unit r) fully in-register. No gate LDS, no
// cross-lane traffic, ONE __syncthreads per epoch, double-buffered h (f16,
// swizzled, 4 rows), x via lagged register pipe.
// L0 K=128: h0|x|bias.  L1 K=224: h0(Wih1)|0|bias|h1(Whh1)|0.

#define T_SEQ 1024

typedef __attribute__((ext_vector_type(8))) _Float16 half8;
typedef __attribute__((ext_vector_type(4))) float f32x4;

__device__ __forceinline__ unsigned short f2h(float f) {
  _Float16 h = (_Float16)f;
  return *reinterpret_cast<unsigned short*>(&h);
}
__device__ __forceinline__ float fast_sig(float x) {
  return __builtin_amdgcn_rcpf(1.0f + __builtin_amdgcn_exp2f(-1.4426950408889634f * x));
}
__device__ __forceinline__ float fast_tanh(float x) {
  return 1.0f - 2.0f * __builtin_amdgcn_rcpf(1.0f + __builtin_amdgcn_exp2f(2.8853900817779268f * x));
}
// element hi of a f32x4, constant-indexed (rule-20 safe): 3 v_cndmask
__device__ __forceinline__ float sel4(f32x4 v, int hi) {
  float t01 = (hi & 1) ? v[1] : v[0];
  float t23 = (hi & 1) ? v[3] : v[2];
  return (hi & 2) ? t23 : t01;
}

// L0 K-layout: [0,100)=Whh0, 100-102=Wih0, 103=bias, else 0.
__device__ __forceinline__ float wval0(int g, int k, const float* Wih, const float* Whh,
                                       const float* bih, const float* bhh) {
  if (k < 100) return Whh[g * 100 + k];
  if (k < 103) return Wih[g * 3 + (k - 100)];
  if (k == 103) return bih[g] + bhh[g];
  return 0.f;
}
// L1 K-layout: [0,100)=Wih1 (h0 input), 103=bias, [104,204)=Whh1, else 0.
__device__ __forceinline__ float wval1(int g, int k, const float* Wih, const float* Whh,
                                       const float* bih, const float* bhh) {
  if (k < 100) return Wih[g * 100 + k];
  if (k == 103) return bih[g] + bhh[g];
  if (k >= 104 && k < 204) return Whh[g * 100 + (k - 104)];
  return 0.f;
}

// hbuf: 2 buffers x 4 rows x 512 B. byte = buf*2048 + row*512 + (2s ^ (row<<4)).
template<bool L0EN, int UB0, bool L1EN, int UB1, bool XST>
__device__ void wave_loop(unsigned short* hbuf, float* h1f,
                          const float* Wih0, const float* Whh0,
                          const float* bih0, const float* bhh0,
                          const float* Wih1, const float* Whh1,
                          const float* bih1, const float* bhh1,
                          const float* x, int b0, int lane) {
  const int r    = lane & 15;     // unit within ublock (B col)
  const int hi   = lane >> 4;     // k-slot group / batch this lane updates
  const int ar   = r & 3;         // replicated A row (batch)
  const int aswz = ar << 4;

  // ---- resident weight B-fragments (init once, pinned) ----
  half8 wf0[L0EN ? 16 : 1];
  if constexpr (L0EN) {
    const int u = UB0 * 16 + r;
    #pragma unroll
    for (int q = 0; q < 4; ++q) {
      const int g = q * 100 + u;
      #pragma unroll
      for (int ks = 0; ks < 4; ++ks) {
        half8 v;
        #pragma unroll
        for (int j = 0; j < 8; ++j) {
          const int k = ks * 32 + hi * 8 + j;
          v[j] = (_Float16)((u < 100) ? wval0(g, k, Wih0, Whh0, bih0, bhh0) : 0.f);
        }
        wf0[q * 4 + ks] = v;
      }
    }
    #pragma unroll
    for (int i = 0; i < 16; ++i) asm volatile("" : "+v"(wf0[i]));
  }
  half8 wf1[L1EN ? 28 : 1];
  if constexpr (L1EN) {
    const int u = UB1 * 16 + r;
    #pragma unroll
    for (int q = 0; q < 4; ++q) {
      const int g = q * 100 + u;
      #pragma unroll
      for (int ks = 0; ks < 7; ++ks) {
        half8 v;
        #pragma unroll
        for (int j = 0; j < 8; ++j) {
          const int k = ks * 32 + hi * 8 + j;
          v[j] = (_Float16)((u < 100) ? wval1(g, k, Wih1, Whh1, bih1, bhh1) : 0.f);
        }
        wf1[q * 7 + ks] = v;
      }
    }
    #pragma unroll
    for (int i = 0; i < 28; ++i) asm volatile("" : "+v"(wf1[i]));
  }

  // ---- x register pipeline (lanes 0-11: 4 rows x 3 ch) ----
  const int bx = lane / 3, ix = lane - 3 * (lane / 3);
  const float* xp = x + (size_t)(b0 + (bx & 3)) * 3072 + ix * 1024;
  float xv0 = 0.f, xv1 = 0.f;
  if (XST && lane < 12) { xv0 = xp[1]; xv1 = xp[2]; }

  float c0 = 0.f, c1 = 0.f;

  for (int e = 0; e <= T_SEQ; ++e) {
    const int p = e & 1;
    const char* rb = reinterpret_cast<const char*>(hbuf) + p * 2048;
    char*       wb = reinterpret_cast<char*>(hbuf) + (p ^ 1) * 2048;

    if constexpr (L0EN) {
      if (e < T_SEQ) {
        half8 a0[4];
        #pragma unroll
        for (int ks = 0; ks < 4; ++ks)
          a0[ks] = *reinterpret_cast<const half8*>(rb + ar * 512 + ((ks * 64 + hi * 16) ^ aswz));
        f32x4 A0{0,0,0,0}, A1{0,0,0,0}, A2{0,0,0,0}, A3{0,0,0,0};
        #pragma unroll
        for (int ks = 0; ks < 4; ++ks) {
          A0 = __builtin_amdgcn_mfma_f32_16x16x32_f16(a0[ks], wf0[0*4+ks], A0, 0,0,0);
          A1 = __builtin_amdgcn_mfma_f32_16x16x32_f16(a0[ks], wf0[1*4+ks], A1, 0,0,0);
          A2 = __builtin_amdgcn_mfma_f32_16x16x32_f16(a0[ks], wf0[2*4+ks], A2, 0,0,0);
          A3 = __builtin_amdgcn_mfma_f32_16x16x32_f16(a0[ks], wf0[3*4+ks], A3, 0,0,0);
        }
        const int u = UB0 * 16 + r;
        if (u < 100) {
          float i_ = fast_sig(sel4(A0, hi));
          float f_ = fast_sig(sel4(A1, hi));
          float g_ = fast_tanh(sel4(A2, hi));
          float o_ = fast_sig(sel4(A3, hi));
          c0 = f_ * c0 + i_ * g_;
          float h = o_ * fast_tanh(c0);
          *reinterpret_cast<unsigned short*>(
              wb + hi * 512 + ((u * 2) ^ (hi << 4))) = f2h(h);
        }
      }
    }
    if constexpr (L1EN) {
      if (e >= 1) {
        half8 a1[7];
        #pragma unroll
        for (int ks = 0; ks < 7; ++ks)
          a1[ks] = *reinterpret_cast<const half8*>(rb + ar * 512 + ((ks * 64 + hi * 16) ^ aswz));
        f32x4 A0{0,0,0,0}, A1{0,0,0,0}, A2{0,0,0,0}, A3{0,0,0,0};
        #pragma unroll
        for (int ks = 0; ks < 7; ++ks) {
          A0 = __builtin_amdgcn_mfma_f32_16x16x32_f16(a1[ks], wf1[0*7+ks], A0, 0,0,0);
          A1 = __builtin_amdgcn_mfma_f32_16x16x32_f16(a1[ks], wf1[1*7+ks], A1, 0,0,0);
          A2 = __builtin_amdgcn_mfma_f32_16x16x32_f16(a1[ks], wf1[2*7+ks], A2, 0,0,0);
          A3 = __builtin_amdgcn_mfma_f32_16x16x32_f16(a1[ks], wf1[3*7+ks], A3, 0,0,0);
        }
        const int u = UB1 * 16 + r;
        if (u < 100) {
          float i_ = fast_sig(sel4(A0, hi));
          float f_ = fast_sig(sel4(A1, hi));
          float g_ = fast_tanh(sel4(A2, hi));
          float o_ = fast_sig(sel4(A3, hi));
          c1 = f_ * c1 + i_ * g_;
          float h = o_ * fast_tanh(c1);
          *reinterpret_cast<unsigned short*>(
              wb + hi * 512 + (((104 + u) * 2) ^ (hi << 4))) = f2h(h);
          if (e == T_SEQ) h1f[hi * 100 + u] = h;
        }
      }
    }
    if (XST && lane < 12 && e + 1 < T_SEQ) {
      // write x[e+1] (loaded >=1 epoch ago -> latency hidden) into write-buf
      *reinterpret_cast<unsigned short*>(
          wb + bx * 512 + (((100 + ix) * 2) ^ (bx << 4))) = f2h(xv0);
      xv0 = xv1;
      if (e + 3 < T_SEQ) xv1 = xp[e + 3];
    }
    __syncthreads();
  }
}

__global__ __launch_bounds__(512, 2)
void lstm2_kernel(const float* __restrict__ x,
                  const float* __restrict__ Wih0, const float* __restrict__ Whh0,
                  const float* __restrict__ bih0, const float* __restrict__ bhh0,
                  const float* __restrict__ Wih1, const float* __restrict__ Whh1,
                  const float* __restrict__ bih1, const float* __restrict__ bhh1,
                  const float* __restrict__ fcw, const float* __restrict__ fcb,
                  float* __restrict__ out) {
  __shared__ __align__(16) unsigned short hbuf[2 * 4 * 256];   // 4 KB dbuf
  __shared__ float h1f[4 * 100];

  const int tid  = threadIdx.x;
  const int lane = tid & 63;
  const int wid  = tid >> 6;
  const int b0   = blockIdx.x << 2;   // 4 batch rows per block

  for (int i = tid; i < 2 * 4 * 256; i += 512) hbuf[i] = 0;
  __syncthreads();
  if (tid < 8) {        // bias slot 103 = f16 1.0, rows 0-3, both buffers
    int tb = tid >> 2, row = tid & 3;
    *reinterpret_cast<unsigned short*>(
        reinterpret_cast<char*>(hbuf) + tb * 2048 + row * 512 +
        ((103 * 2) ^ (row << 4))) = 0x3C00u;
  }
  if (tid >= 64 && tid < 76) {   // x[t=0] into buf0
    int s = tid - 64;
    int b = s / 3, i = s - 3 * (s / 3);
    *reinterpret_cast<unsigned short*>(
        reinterpret_cast<char*>(hbuf) + b * 512 +
        (((100 + i) * 2) ^ (b << 4))) =
        f2h(x[(size_t)(b0 + b) * 3072 + i * 1024]);
  }
  __syncthreads();

  if      (wid == 0) wave_loop<true,0,true,0,false>(hbuf,h1f,Wih0,Whh0,bih0,bhh0,Wih1,Whh1,bih1,bhh1,x,b0,lane);
  else if (wid == 1) wave_loop<true,1,true,1,false>(hbuf,h1f,Wih0,Whh0,bih0,bhh0,Wih1,Whh1,bih1,bhh1,x,b0,lane);
  else if (wid == 2) wave_loop<true,2,true,2,false>(hbuf,h1f,Wih0,Whh0,bih0,bhh0,Wih1,Whh1,bih1,bhh1,x,b0,lane);
  else if (wid == 3) wave_loop<true,3,true,3,false>(hbuf,h1f,Wih0,Whh0,bih0,bhh0,Wih1,Whh1,bih1,bhh1,x,b0,lane);
  else if (wid == 4) wave_loop<true,4,true,4,false>(hbuf,h1f,Wih0,Whh0,bih0,bhh0,Wih1,Whh1,bih1,bhh1,x,b0,lane);
  else if (wid == 5) wave_loop<true,5,true,5,false>(hbuf,h1f,Wih0,Whh0,bih0,bhh0,Wih1,Whh1,bih1,bhh1,x,b0,lane);
  else if (wid == 6) wave_loop<true,6,false,0,true>(hbuf,h1f,Wih0,Whh0,bih0,bhh0,Wih1,Whh1,bih1,bhh1,x,b0,lane);
  else               wave_loop<false,0,true,6,false>(hbuf,h1f,Wih0,Whh0,bih0,bhh0,Wih1,Whh1,bih1,bhh1,x,b0,lane);

  // ---- FC: out[b][j] = fc_b[j] + sum_u fc_w[j][u] * h1[T-1][b][u] ----
  if (tid < 40) {
    int b = tid / 10, j = tid - 10 * (tid / 10);
    float acc = fcb[j];
    for (int u = 0; u < 100; ++u)
      acc += fcw[j * 100 + u] * h1f[b * 100 + u];
    out[(size_t)(b0 + b) * 10 + j] = acc;
  }
}

extern "C" void kernel_launch(void* const* d_in, const int* in_sizes, int n_in,
                              void* d_out, int out_size, void* d_ws, size_t ws_size,
                              hipStream_t stream) {
  (void)in_sizes; (void)n_in; (void)d_ws; (void)ws_size; (void)out_size;
  const float* x    = (const float*)d_in[0];
  const float* Wih0 = (const float*)d_in[1];
  const float* Whh0 = (const float*)d_in[2];
  const float* bih0 = (const float*)d_in[3];
  const float* bhh0 = (const float*)d_in[4];
  const float* Wih1 = (const float*)d_in[5];
  const float* Whh1 = (const float*)d_in[6];
  const float* bih1 = (const float*)d_in[7];
  const float* bhh1 = (const float*)d_in[8];
  const float* fcw  = (const float*)d_in[9];
  const float* fcb  = (const float*)d_in[10];
  hipLaunchKernelGGL(lstm2_kernel, dim3(256), dim3(512), 0, stream,
                     x, Wih0, Whh0, bih0, bhh0, Wih1, Whh1, bih1, bhh1,
                     fcw, fcb, (float*)d_out);
}

// Round 8
// 1101.864 us; speedup vs baseline: 2.1113x; 1.0080x over previous
//
#include <hip/hip_runtime.h>
#include <hip/hip_fp16.h>

// 2-layer LSTM (T=1024, B=1024, H=100) + FC. R7 = R6 structure + register fix.
// 256 blocks x 4 batch rows, 512 threads (8 waves, 2/SIMD).
// amdgpu_waves_per_eu(2,2) pins the allocator to 256 VGPR/wave so the
// register-resident weights (dual-job waves: 176 VGPR) do NOT spill.
// Batch-row replication: A-fragment reads row (r&3) -> each lane holds
// batches 0-3 of unit r in its 4 acc elements -> select by hi, update
// (batch hi, unit r) fully in-register. Row stride 576 B (=> 2-way max
// bank aliasing, free) replaces the XOR swizzle. ONE barrier per epoch,
// double-buffered h (f16), x via lagged register pipe.
// L0 K=128: h0|x|bias|(h1 junk * zero-weights). L1 K=224: h0|x-junk*0|bias|h1|0.

#define T_SEQ 1024
#define ROWB 576                 // bytes per row (36*16, 16B-aligned)
#define BUFB (4 * ROWB)          // bytes per buffer (4 rows)

typedef __attribute__((ext_vector_type(8))) _Float16 half8;
typedef __attribute__((ext_vector_type(4))) float f32x4;

__device__ __forceinline__ unsigned short f2h(float f) {
  _Float16 h = (_Float16)f;
  return *reinterpret_cast<unsigned short*>(&h);
}
__device__ __forceinline__ float fast_sig(float x) {
  return __builtin_amdgcn_rcpf(1.0f + __builtin_amdgcn_exp2f(-1.4426950408889634f * x));
}
__device__ __forceinline__ float fast_tanh(float x) {
  return 1.0f - 2.0f * __builtin_amdgcn_rcpf(1.0f + __builtin_amdgcn_exp2f(2.8853900817779268f * x));
}
// element hi of a f32x4, constant-indexed: 3 v_cndmask
__device__ __forceinline__ float sel4(f32x4 v, int hi) {
  float t01 = (hi & 1) ? v[1] : v[0];
  float t23 = (hi & 1) ? v[3] : v[2];
  return (hi & 2) ? t23 : t01;
}

// L0 K-layout: [0,100)=Whh0, 100-102=Wih0, 103=bias, else 0.
__device__ __forceinline__ float wval0(int g, int k, const float* Wih, const float* Whh,
                                       const float* bih, const float* bhh) {
  if (k < 100) return Whh[g * 100 + k];
  if (k < 103) return Wih[g * 3 + (k - 100)];
  if (k == 103) return bih[g] + bhh[g];
  return 0.f;
}
// L1 K-layout: [0,100)=Wih1 (h0 input), 103=bias, [104,204)=Whh1, else 0.
__device__ __forceinline__ float wval1(int g, int k, const float* Wih, const float* Whh,
                                       const float* bih, const float* bhh) {
  if (k < 100) return Wih[g * 100 + k];
  if (k == 103) return bih[g] + bhh[g];
  if (k >= 104 && k < 204) return Whh[g * 100 + (k - 104)];
  return 0.f;
}

// hbuf: 2 buffers x 4 rows x ROWB. slot s of row b: byte = buf*BUFB + b*ROWB + 2s.
template<bool L0EN, int UB0, bool L1EN, int UB1, bool XST>
__device__ void wave_loop(unsigned short* hbuf, float* h1f,
                          const float* Wih0, const float* Whh0,
                          const float* bih0, const float* bhh0,
                          const float* Wih1, const float* Whh1,
                          const float* bih1, const float* bhh1,
                          const float* x, int b0, int lane) {
  const int r  = lane & 15;     // unit within ublock (B col)
  const int hi = lane >> 4;     // k-slot group / batch this lane updates
  const int ar = r & 3;         // replicated A row (batch)

  // ---- resident weight B-fragments (init once) ----
  half8 wf0[L0EN ? 16 : 1];
  if constexpr (L0EN) {
    const int u = UB0 * 16 + r;
    #pragma unroll
    for (int q = 0; q < 4; ++q) {
      const int g = q * 100 + u;
      #pragma unroll
      for (int ks = 0; ks < 4; ++ks) {
        half8 v;
        #pragma unroll
        for (int j = 0; j < 8; ++j) {
          const int k = ks * 32 + hi * 8 + j;
          v[j] = (_Float16)((u < 100) ? wval0(g, k, Wih0, Whh0, bih0, bhh0) : 0.f);
        }
        wf0[q * 4 + ks] = v;
      }
    }
  }
  half8 wf1[L1EN ? 28 : 1];
  if constexpr (L1EN) {
    const int u = UB1 * 16 + r;
    #pragma unroll
    for (int q = 0; q < 4; ++q) {
      const int g = q * 100 + u;
      #pragma unroll
      for (int ks = 0; ks < 7; ++ks) {
        half8 v;
        #pragma unroll
        for (int j = 0; j < 8; ++j) {
          const int k = ks * 32 + hi * 8 + j;
          v[j] = (_Float16)((u < 100) ? wval1(g, k, Wih1, Whh1, bih1, bhh1) : 0.f);
        }
        wf1[q * 7 + ks] = v;
      }
    }
  }

  // ---- x register pipeline (lanes 0-11: 4 rows x 3 ch) ----
  const int bx = lane / 3, ix = lane - 3 * (lane / 3);
  const float* xp = x + (size_t)(b0 + (bx & 3)) * 3072 + ix * 1024;
  float xv0 = 0.f, xv1 = 0.f;
  if (XST && lane < 12) { xv0 = xp[1]; xv1 = xp[2]; }

  float c0 = 0.f, c1 = 0.f;
  constexpr int NKS = L1EN ? 7 : 4;

  for (int e = 0; e <= T_SEQ; ++e) {
    const int p = e & 1;
    const char* rb = reinterpret_cast<const char*>(hbuf) + p * BUFB;
    char*       wb = reinterpret_cast<char*>(hbuf) + (p ^ 1) * BUFB;

    // A-fragments shared by both jobs (L1's first 4 k-slots == L0's 4).
    half8 a[NKS];
    #pragma unroll
    for (int ks = 0; ks < NKS; ++ks)
      a[ks] = *reinterpret_cast<const half8*>(rb + ar * ROWB + ks * 64 + hi * 16);

    if constexpr (L0EN) {
      if (e < T_SEQ) {
        f32x4 A0{0,0,0,0}, A1{0,0,0,0}, A2{0,0,0,0}, A3{0,0,0,0};
        #pragma unroll
        for (int ks = 0; ks < 4; ++ks) {
          A0 = __builtin_amdgcn_mfma_f32_16x16x32_f16(a[ks], wf0[0*4+ks], A0, 0,0,0);
          A1 = __builtin_amdgcn_mfma_f32_16x16x32_f16(a[ks], wf0[1*4+ks], A1, 0,0,0);
          A2 = __builtin_amdgcn_mfma_f32_16x16x32_f16(a[ks], wf0[2*4+ks], A2, 0,0,0);
          A3 = __builtin_amdgcn_mfma_f32_16x16x32_f16(a[ks], wf0[3*4+ks], A3, 0,0,0);
        }
        const int u = UB0 * 16 + r;
        if (u < 100) {
          float i_ = fast_sig(sel4(A0, hi));
          float f_ = fast_sig(sel4(A1, hi));
          float g_ = fast_tanh(sel4(A2, hi));
          float o_ = fast_sig(sel4(A3, hi));
          c0 = f_ * c0 + i_ * g_;
          float h = o_ * fast_tanh(c0);
          *reinterpret_cast<unsigned short*>(wb + hi * ROWB + u * 2) = f2h(h);
        }
      }
    }
    if constexpr (L1EN) {
      if (e >= 1) {
        f32x4 A0{0,0,0,0}, A1{0,0,0,0}, A2{0,0,0,0}, A3{0,0,0,0};
        #pragma unroll
        for (int ks = 0; ks < 7; ++ks) {
          A0 = __builtin_amdgcn_mfma_f32_16x16x32_f16(a[ks], wf1[0*7+ks], A0, 0,0,0);
          A1 = __builtin_amdgcn_mfma_f32_16x16x32_f16(a[ks], wf1[1*7+ks], A1, 0,0,0);
          A2 = __builtin_amdgcn_mfma_f32_16x16x32_f16(a[ks], wf1[2*7+ks], A2, 0,0,0);
          A3 = __builtin_amdgcn_mfma_f32_16x16x32_f16(a[ks], wf1[3*7+ks], A3, 0,0,0);
        }
        const int u = UB1 * 16 + r;
        if (u < 100) {
          float i_ = fast_sig(sel4(A0, hi));
          float f_ = fast_sig(sel4(A1, hi));
          float g_ = fast_tanh(sel4(A2, hi));
          float o_ = fast_sig(sel4(A3, hi));
          c1 = f_ * c1 + i_ * g_;
          float h = o_ * fast_tanh(c1);
          *reinterpret_cast<unsigned short*>(wb + hi * ROWB + (104 + u) * 2) = f2h(h);
          if (e == T_SEQ) h1f[hi * 100 + u] = h;
        }
      }
    }
    if (XST && lane < 12 && e + 1 < T_SEQ) {
      // write x[e+1] (loaded >=2 epochs ago -> latency hidden) into write-buf
      *reinterpret_cast<unsigned short*>(wb + bx * ROWB + (100 + ix) * 2) = f2h(xv0);
      xv0 = xv1;
      if (e + 3 < T_SEQ) xv1 = xp[e + 3];
    }
    __syncthreads();
  }
}

__global__ __attribute__((amdgpu_flat_work_group_size(512, 512),
                          amdgpu_waves_per_eu(2, 2)))
void lstm2_kernel(const float* __restrict__ x,
                  const float* __restrict__ Wih0, const float* __restrict__ Whh0,
                  const float* __restrict__ bih0, const float* __restrict__ bhh0,
                  const float* __restrict__ Wih1, const float* __restrict__ Whh1,
                  const float* __restrict__ bih1, const float* __restrict__ bhh1,
                  const float* __restrict__ fcw, const float* __restrict__ fcb,
                  float* __restrict__ out) {
  __shared__ __align__(16) unsigned short hbuf[2 * BUFB / 2];  // 4.5 KB dbuf
  __shared__ float h1f[4 * 100];

  const int tid  = threadIdx.x;
  const int lane = tid & 63;
  const int wid  = tid >> 6;
  const int b0   = blockIdx.x << 2;   // 4 batch rows per block

  for (int i = tid; i < BUFB; i += 512) hbuf[i] = 0;   // BUFB shorts = 2*BUFB bytes total
  __syncthreads();
  if (tid < 8) {        // bias slot 103 = f16 1.0, rows 0-3, both buffers
    int tb = tid >> 2, row = tid & 3;
    *reinterpret_cast<unsigned short*>(
        reinterpret_cast<char*>(hbuf) + tb * BUFB + row * ROWB + 103 * 2) = 0x3C00u;
  }
  if (tid >= 64 && tid < 76) {   // x[t=0] into buf0
    int s = tid - 64;
    int b = s / 3, i = s - 3 * (s / 3);
    *reinterpret_cast<unsigned short*>(
        reinterpret_cast<char*>(hbuf) + b * ROWB + (100 + i) * 2) =
        f2h(x[(size_t)(b0 + b) * 3072 + i * 1024]);
  }
  __syncthreads();

  if      (wid == 0) wave_loop<true,0,true,0,false>(hbuf,h1f,Wih0,Whh0,bih0,bhh0,Wih1,Whh1,bih1,bhh1,x,b0,lane);
  else if (wid == 1) wave_loop<true,1,true,1,false>(hbuf,h1f,Wih0,Whh0,bih0,bhh0,Wih1,Whh1,bih1,bhh1,x,b0,lane);
  else if (wid == 2) wave_loop<true,2,true,2,false>(hbuf,h1f,Wih0,Whh0,bih0,bhh0,Wih1,Whh1,bih1,bhh1,x,b0,lane);
  else if (wid == 3) wave_loop<true,3,true,3,false>(hbuf,h1f,Wih0,Whh0,bih0,bhh0,Wih1,Whh1,bih1,bhh1,x,b0,lane);
  else if (wid == 4) wave_loop<true,4,true,4,false>(hbuf,h1f,Wih0,Whh0,bih0,bhh0,Wih1,Whh1,bih1,bhh1,x,b0,lane);
  else if (wid == 5) wave_loop<true,5,true,5,false>(hbuf,h1f,Wih0,Whh0,bih0,bhh0,Wih1,Whh1,bih1,bhh1,x,b0,lane);
  else if (wid == 6) wave_loop<true,6,false,0,true>(hbuf,h1f,Wih0,Whh0,bih0,bhh0,Wih1,Whh1,bih1,bhh1,x,b0,lane);
  else               wave_loop<false,0,true,6,false>(hbuf,h1f,Wih0,Whh0,bih0,bhh0,Wih1,Whh1,bih1,bhh1,x,b0,lane);

  // ---- FC: out[b][j] = fc_b[j] + sum_u fc_w[j][u] * h1[T-1][b][u] ----
  if (tid < 40) {
    int b = tid / 10, j = tid - 10 * (tid / 10);
    float acc = fcb[j];
    for (int u = 0; u < 100; ++u)
      acc += fcw[j * 100 + u] * h1f[b * 100 + u];
    out[(size_t)(b0 + b) * 10 + j] = acc;
  }
}

extern "C" void kernel_launch(void* const* d_in, const int* in_sizes, int n_in,
                              void* d_out, int out_size, void* d_ws, size_t ws_size,
                              hipStream_t stream) {
  (void)in_sizes; (void)n_in; (void)d_ws; (void)ws_size; (void)out_size;
  const float* x    = (const float*)d_in[0];
  const float* Wih0 = (const float*)d_in[1];
  const float* Whh0 = (const float*)d_in[2];
  const float* bih0 = (const float*)d_in[3];
  const float* bhh0 = (const float*)d_in[4];
  const float* Wih1 = (const float*)d_in[5];
  const float* Whh1 = (const float*)d_in[6];
  const float* bih1 = (const float*)d_in[7];
  const float* bhh1 = (const float*)d_in[8];
  const float* fcw  = (const float*)d_in[9];
  const float* fcb  = (const float*)d_in[10];
  hipLaunchKernelGGL(lstm2_kernel, dim3(256), dim3(512), 0, stream,
                     x, Wih0, Whh0, bih0, bhh0, Wih1, Whh1, bih1, bhh1,
                     fcw, fcb, (float*)d_out);
}